// Round 8
// baseline (315.411 us; speedup 1.0000x reference)
//
#include <hip/hip_runtime.h>

typedef float v2f __attribute__((ext_vector_type(2)));

#define NROWS_GRID 16
#define GB 512

// ---- fp8 helpers (hw cvt; self-consistent encode/decode) ----
__device__ inline unsigned pack4_fp8(float a, float b, float c, float d) {
    int t = __builtin_amdgcn_cvt_pk_fp8_f32(a, b, 0, false);   // bytes [1:0]
    t     = __builtin_amdgcn_cvt_pk_fp8_f32(c, d, t, true);    // bytes [3:2]
    return (unsigned)t;
}

// ---------------- quantize table f32[n,172] -> fp8 rows padded to 176B ----------------
__global__ __launch_bounds__(256) void quant_tab(
    const float* __restrict__ src,   // [n,172]
    uint4*       __restrict__ dst,   // [n,11]  (176B rows)
    int n)
{
    int i = blockIdx.x * 256 + threadIdx.x;
    int row = i / 11, c = i - row * 11;
    if (row >= n) return;
    const float4* s = (const float4*)(src + (size_t)row * 172);
    float v[16];
    if (c < 10) {
        #pragma unroll
        for (int j = 0; j < 4; ++j) {
            float4 f = s[4 * c + j];
            v[4*j+0] = f.x; v[4*j+1] = f.y; v[4*j+2] = f.z; v[4*j+3] = f.w;
        }
    } else {
        #pragma unroll
        for (int j = 0; j < 3; ++j) {
            float4 f = s[40 + j];
            v[4*j+0] = f.x; v[4*j+1] = f.y; v[4*j+2] = f.z; v[4*j+3] = f.w;
        }
        v[12] = v[13] = v[14] = v[15] = 0.f;
    }
    uint4 o;
    o.x = pack4_fp8(v[0],  v[1],  v[2],  v[3]);
    o.y = pack4_fp8(v[4],  v[5],  v[6],  v[7]);
    o.z = pack4_fp8(v[8],  v[9],  v[10], v[11]);
    o.w = pack4_fp8(v[12], v[13], v[14], v[15]);
    dst[(size_t)row * 11 + c] = o;
}

// ---------------- gather+mean from fp8 table -> inpw[grow][base+16c .. ] ----------------
// item i in [0, 16384*11): grow = i/11, c = i%11
__global__ __launch_bounds__(256) void gather_q(
    const uint4* __restrict__ Q,      // [n,11]
    const int*   __restrict__ s_ids,  // [8192,32]
    const int*   __restrict__ d_ids,
    float*       __restrict__ inpw,   // [16384,616]
    int baseoff)                      // 172 (node) or 344 (edge)
{
    int i    = blockIdx.x * 256 + threadIdx.x;
    int grow = i / 11, c = i - grow * 11;
    int side = grow >> 13, row = grow & 8191;
    const int4* idv = (const int4*)&((side ? d_ids : s_ids)[row * 32]);

    float acc[16];
    #pragma unroll
    for (int k = 0; k < 16; ++k) acc[k] = 0.f;

    #pragma unroll
    for (int b = 0; b < 4; ++b) {
        int4 q0 = idv[2 * b], q1 = idv[2 * b + 1];
        int off[8] = {q0.x, q0.y, q0.z, q0.w, q1.x, q1.y, q1.z, q1.w};
        uint4 v[8];
        #pragma unroll
        for (int u = 0; u < 8; ++u)
            v[u] = Q[(size_t)off[u] * 11 + c];
        #pragma unroll
        for (int u = 0; u < 8; ++u) {
            unsigned w[4] = {v[u].x, v[u].y, v[u].z, v[u].w};
            #pragma unroll
            for (int q = 0; q < 4; ++q) {
                v2f lo = __builtin_amdgcn_cvt_pk_f32_fp8((int)w[q], false);
                v2f hi = __builtin_amdgcn_cvt_pk_f32_fp8((int)w[q], true);
                acc[4*q+0] += lo.x; acc[4*q+1] += lo.y;
                acc[4*q+2] += hi.x; acc[4*q+3] += hi.y;
            }
        }
    }

    float* dstrow = inpw + (size_t)grow * 616 + baseoff + 16 * c;
    int nf4 = (c == 10) ? 3 : 4;
    for (int j = 0; j < nf4; ++j) {
        float4 o = { acc[4*j+0] * (1.f/32.f), acc[4*j+1] * (1.f/32.f),
                     acc[4*j+2] * (1.f/32.f), acc[4*j+3] * (1.f/32.f) };
        *(float4*)(dstrow + 4 * j) = o;
    }
}

// ---------------- cur-node copy (f32 gather, 16384 rows) ----------------
__global__ __launch_bounds__(256) void cur_copy(
    const float* __restrict__ nodef,
    const int*   __restrict__ src_ids,
    const int*   __restrict__ dst_ids,
    float*       __restrict__ inpw)
{
    int i    = blockIdx.x * 256 + threadIdx.x;   // 16384*43 items
    int grow = i / 43, c = i - grow * 43;
    int side = grow >> 13, row = grow & 8191;
    int id   = (side ? dst_ids : src_ids)[row];
    *(float4*)(inpw + (size_t)grow * 616 + 4 * c) =
        *(const float4*)(nodef + (size_t)id * 172 + 4 * c);
}

// ---------------- time encoding (f32) ----------------
__global__ __launch_bounds__(256) void time_enc(
    const int*   __restrict__ s_nbr,
    const int*   __restrict__ d_nbr,
    const float* __restrict__ s_t,
    const float* __restrict__ d_t,
    const float* __restrict__ itimes,
    const float* __restrict__ tw,
    const float* __restrict__ tb,
    float*       __restrict__ inpw)
{
    int i    = blockIdx.x * 256 + threadIdx.x;   // 16384*100 items
    int grow = i / 100, j = i - grow * 100;
    int side = grow >> 13, row = grow & 8191;
    const int*   nbr = (side ? d_nbr : s_nbr) + row * 32;
    const float* nt  = (side ? d_t   : s_t)   + row * 32;
    float it = itimes[row];
    float w = tw[j], b = tb[j];
    float acc = 0.f;
    #pragma unroll
    for (int s = 0; s < 32; ++s) {
        float m = (nbr[s] == 0) ? 0.f : 1.f;
        acc += m * __cosf((it - nt[s]) * w + b);
    }
    inpw[(size_t)grow * 616 + 516 + j] = acc * (1.f / 32.f);
}

// ---------------- dense GEMM: out = relu(inpw @ W + b) ----------------
__global__ __launch_bounds__(GB) void final_gemm(
    const float* __restrict__ inpw,   // [16384,616]
    const float* __restrict__ W,      // [616,172]
    const float* __restrict__ bout,   // [172]
    float*       __restrict__ out)    // [3,8192,172]
{
    __shared__ float inp[NROWS_GRID * 620];   // stride 620: rt-groups land 2-way on banks (free)
    const int tid      = threadIdx.x;
    const int side     = blockIdx.x >> 9;
    const int rowbase  = (blockIdx.x & 511) * NROWS_GRID;
    const int growbase = side * 8192 + rowbase;

    for (int i = tid; i < NROWS_GRID * 154; i += GB) {
        int r = i / 154, c = i - r * 154;
        *(float4*)&inp[r * 620 + 4 * c] =
            *(const float4*)&inpw[(size_t)(growbase + r) * 616 + 4 * c];
    }
    __syncthreads();

    // 344 threads = 8 row-tiles x 43 col-tiles, each thread 2 rows x 4 cols
    if (tid < 344) {
        const int ct = tid % 43, rt = tid / 43;
        const int j0 = ct * 4, r0 = rt * 2;
        float acc[2][4] = {};
        float a[2][4];
        for (int k = 0; k < 616; k += 4) {
            #pragma unroll
            for (int ri = 0; ri < 2; ++ri)
                *(float4*)&a[ri][0] = *(const float4*)&inp[(r0 + ri) * 620 + k];
            #pragma unroll
            for (int kk = 0; kk < 4; ++kk) {
                float4 wv = *(const float4*)&W[(k + kk) * 172 + j0];
                #pragma unroll
                for (int ri = 0; ri < 2; ++ri) {
                    acc[ri][0] += a[ri][kk] * wv.x;
                    acc[ri][1] += a[ri][kk] * wv.y;
                    acc[ri][2] += a[ri][kk] * wv.z;
                    acc[ri][3] += a[ri][kk] * wv.w;
                }
            }
        }
        float4 bias = *(const float4*)&bout[j0];
        #pragma unroll
        for (int ri = 0; ri < 2; ++ri) {
            int row = rowbase + r0 + ri;
            float4 v;
            v.x = fmaxf(acc[ri][0] + bias.x, 0.f);
            v.y = fmaxf(acc[ri][1] + bias.y, 0.f);
            v.z = fmaxf(acc[ri][2] + bias.z, 0.f);
            v.w = fmaxf(acc[ri][3] + bias.w, 0.f);
            *(float4*)&out[(size_t)(side * 8192 + row) * 172 + j0] = v;
        }
    }

    if (side == 0) {
        const float4 z = {0.f, 0.f, 0.f, 0.f};
        for (int i = tid; i < NROWS_GRID * 43; i += GB) {
            int r = i / 43, c = i - r * 43;
            *(float4*)&out[(size_t)(2 * 8192 + rowbase + r) * 172 + 4 * c] = z;
        }
    }
}

extern "C" void kernel_launch(void* const* d_in, const int* in_sizes, int n_in,
                              void* d_out, int out_size, void* d_ws, size_t ws_size,
                              hipStream_t stream) {
    const float* nodef   = (const float*)d_in[0];
    const float* edgef   = (const float*)d_in[1];
    const int*   src_ids = (const int*)  d_in[2];
    const int*   dst_ids = (const int*)  d_in[3];
    const float* itimes  = (const float*)d_in[4];
    const int*   s_nbr   = (const int*)  d_in[5];
    const int*   s_eid   = (const int*)  d_in[6];
    const float* s_t     = (const float*)d_in[7];
    const int*   d_nbr   = (const int*)  d_in[8];
    const int*   d_eid   = (const int*)  d_in[9];
    const float* d_t     = (const float*)d_in[10];
    const float* tw      = (const float*)d_in[11];
    const float* tb      = (const float*)d_in[12];
    const float* W       = (const float*)d_in[13];
    const float* bout    = (const float*)d_in[14];
    float* out = (float*)d_out;

    // ws layout: inpw f32[16384,616] @0 (40.4MB); nodeQ @48MB (35.2MB); edgeQ @96MB (88MB)
    char*  ws    = (char*)d_ws;
    float* inpw  = (float*)ws;
    uint4* nodeQ = (uint4*)(ws + (size_t)48  * 1024 * 1024);
    uint4* edgeQ = (uint4*)(ws + (size_t)96  * 1024 * 1024);

    // node: quantize then gather while L3-hot (35MB fully L3-resident)
    quant_tab<<<8594, 256, 0, stream>>>(nodef, nodeQ, 200000);
    gather_q<<<704, 256, 0, stream>>>(nodeQ, s_nbr, d_nbr, inpw, 172);

    // edge: quantize then gather (88MB L3-resident)
    quant_tab<<<21485, 256, 0, stream>>>(edgef, edgeQ, 500000);
    gather_q<<<704, 256, 0, stream>>>(edgeQ, s_eid, d_eid, inpw, 344);

    // f32 parts
    cur_copy<<<2752, 256, 0, stream>>>(nodef, src_ids, dst_ids, inpw);
    time_enc<<<6400, 256, 0, stream>>>(s_nbr, d_nbr, s_t, d_t, itimes, tw, tb, inpw);

    // dense GEMM + ReLU + dummy zeros
    final_gemm<<<1024, GB, 0, stream>>>(inpw, W, bout, out);
}

// Round 9
// 226.573 us; speedup vs baseline: 1.3921x; 1.3921x over previous
//
#include <hip/hip_runtime.h>

#define ROWS  8
#define BLOCK 256
#define PAD   620   // 616 padded; 2480B row, 16B-aligned

__global__ __launch_bounds__(BLOCK) void spe_fused(
    const float* __restrict__ nodef,   // [200000,172]
    const float* __restrict__ edgef,   // [500000,172]
    const int*   __restrict__ src_ids, // [8192]
    const int*   __restrict__ dst_ids, // [8192]
    const float* __restrict__ itimes,  // [8192]
    const int*   __restrict__ s_nbr,   // [8192,32]
    const int*   __restrict__ s_eid,   // [8192,32]
    const float* __restrict__ s_t,     // [8192,32]
    const int*   __restrict__ d_nbr,
    const int*   __restrict__ d_eid,
    const float* __restrict__ d_t,
    const float* __restrict__ tw,      // [100]
    const float* __restrict__ tb,      // [100]
    const float* __restrict__ W,       // [616,172]
    const float* __restrict__ bout,    // [172]
    float*       __restrict__ out)     // [3,8192,172]
{
    __shared__ float inp[ROWS * PAD];     // ~19.4KB
    __shared__ int   noff[ROWS * 32];
    __shared__ int   eoff[ROWS * 32];
    __shared__ float dtm[ROWS * 32];
    __shared__ float msk[ROWS * 32];
    __shared__ int   curoff[ROWS];
    __shared__ float twl[100], tbl[100];

    const int tid     = threadIdx.x;
    const int side    = blockIdx.x >> 10;            // 1024 blocks per side
    const int rowbase = (blockIdx.x & 1023) * ROWS;

    const int*   nbr  = side ? d_nbr : s_nbr;
    const int*   eidp = side ? d_eid : s_eid;
    const float* ntp  = side ? d_t   : s_t;
    const int*   nids = side ? dst_ids : src_ids;

    // ---- stage ids / dt / mask (ROWS*32 == 256 == BLOCK: one item each) ----
    {
        int i   = tid;
        int g   = rowbase * 32 + i;
        int nid = nbr[g];
        noff[i] = nid * 172;
        eoff[i] = eidp[g] * 172;
        dtm[i]  = itimes[rowbase + (i >> 5)] - ntp[g];
        msk[i]  = (nid == 0) ? 0.f : 1.f;
    }
    if (tid < ROWS) curoff[tid] = nids[rowbase + tid] * 172;
    if (tid < 100) { twl[tid] = tw[tid]; tbl[tid] = tb[tid]; }
    __syncthreads();

    // ---- cur node copy (float4): inp[r][0:172] ---- (no barrier needed until GEMM)
    for (int i = tid; i < ROWS * 43; i += BLOCK) {
        int r = i / 43, c = i - r * 43;
        *(float4*)&inp[r * PAD + 4 * c] =
            *(const float4*)&nodef[curoff[r] + 4 * c];
    }

    // ---- node gather mean (float4, 8 loads in flight): inp[r][172+d] ----
    for (int i = tid; i < ROWS * 43; i += BLOCK) {
        int r = i / 43, c = i - r * 43;
        const int dd = 4 * c, rb = r * 32;
        float4 acc = {0.f, 0.f, 0.f, 0.f};
        #pragma unroll
        for (int s0 = 0; s0 < 32; s0 += 8) {
            float4 v[8];
            #pragma unroll
            for (int u = 0; u < 8; ++u)
                v[u] = *(const float4*)&nodef[noff[rb + s0 + u] + dd];
            #pragma unroll
            for (int u = 0; u < 8; ++u) {
                acc.x += v[u].x; acc.y += v[u].y;
                acc.z += v[u].z; acc.w += v[u].w;
            }
        }
        acc.x *= (1.f/32.f); acc.y *= (1.f/32.f);
        acc.z *= (1.f/32.f); acc.w *= (1.f/32.f);
        *(float4*)&inp[r * PAD + 172 + dd] = acc;
    }

    // ---- edge gather mean (float4, 8 loads in flight): inp[r][344+d] ----
    for (int i = tid; i < ROWS * 43; i += BLOCK) {
        int r = i / 43, c = i - r * 43;
        const int dd = 4 * c, rb = r * 32;
        float4 acc = {0.f, 0.f, 0.f, 0.f};
        #pragma unroll
        for (int s0 = 0; s0 < 32; s0 += 8) {
            float4 v[8];
            #pragma unroll
            for (int u = 0; u < 8; ++u)
                v[u] = *(const float4*)&edgef[eoff[rb + s0 + u] + dd];
            #pragma unroll
            for (int u = 0; u < 8; ++u) {
                acc.x += v[u].x; acc.y += v[u].y;
                acc.z += v[u].z; acc.w += v[u].w;
            }
        }
        acc.x *= (1.f/32.f); acc.y *= (1.f/32.f);
        acc.z *= (1.f/32.f); acc.w *= (1.f/32.f);
        *(float4*)&inp[r * PAD + 344 + dd] = acc;
    }

    // ---- time encoding: inp[r][516+j] ----
    for (int i = tid; i < ROWS * 100; i += BLOCK) {
        int r = i / 100, j = i - r * 100;
        const int rb = r * 32;
        float w = twl[j], b = tbl[j];
        float acc = 0.f;
        #pragma unroll
        for (int s = 0; s < 32; ++s)
            acc += msk[rb + s] * __cosf(dtm[rb + s] * w + b);
        inp[r * PAD + 516 + j] = acc * (1.f / 32.f);
    }
    __syncthreads();

    // ---- GEMM: out[8,172] = relu(inp[8,616] @ W[616,172] + b) ----
    // 172 threads = 4 row-tiles x 43 col-tiles, each thread 2 rows x 4 cols
    if (tid < 172) {
        const int ct = tid % 43, rt = tid / 43;
        const int j0 = ct * 4, r0 = rt * 2;
        float acc[2][4] = {};
        float a[2][4];
        for (int k = 0; k < 616; k += 4) {
            #pragma unroll
            for (int ri = 0; ri < 2; ++ri)
                *(float4*)&a[ri][0] = *(const float4*)&inp[(r0 + ri) * PAD + k];
            #pragma unroll
            for (int kk = 0; kk < 4; ++kk) {
                float4 wv = *(const float4*)&W[(k + kk) * 172 + j0];
                #pragma unroll
                for (int ri = 0; ri < 2; ++ri) {
                    acc[ri][0] += a[ri][kk] * wv.x;
                    acc[ri][1] += a[ri][kk] * wv.y;
                    acc[ri][2] += a[ri][kk] * wv.z;
                    acc[ri][3] += a[ri][kk] * wv.w;
                }
            }
        }
        float4 bias = *(const float4*)&bout[j0];
        #pragma unroll
        for (int ri = 0; ri < 2; ++ri) {
            int row = rowbase + r0 + ri;
            float4 v;
            v.x = fmaxf(acc[ri][0] + bias.x, 0.f);
            v.y = fmaxf(acc[ri][1] + bias.y, 0.f);
            v.z = fmaxf(acc[ri][2] + bias.z, 0.f);
            v.w = fmaxf(acc[ri][3] + bias.w, 0.f);
            *(float4*)&out[(size_t)(side * 8192 + row) * 172 + j0] = v;
        }
    }

    // ---- dummy third output = zeros (side-0 blocks) ----
    if (side == 0) {
        const float4 z = {0.f, 0.f, 0.f, 0.f};
        for (int i = tid; i < ROWS * 43; i += BLOCK) {
            int r = i / 43, c = i - r * 43;
            *(float4*)&out[(size_t)(2 * 8192 + rowbase + r) * 172 + 4 * c] = z;
        }
    }
}

extern "C" void kernel_launch(void* const* d_in, const int* in_sizes, int n_in,
                              void* d_out, int out_size, void* d_ws, size_t ws_size,
                              hipStream_t stream) {
    const float* nodef   = (const float*)d_in[0];
    const float* edgef   = (const float*)d_in[1];
    const int*   src_ids = (const int*)  d_in[2];
    const int*   dst_ids = (const int*)  d_in[3];
    const float* itimes  = (const float*)d_in[4];
    const int*   s_nbr   = (const int*)  d_in[5];
    const int*   s_eid   = (const int*)  d_in[6];
    const float* s_t     = (const float*)d_in[7];
    const int*   d_nbr   = (const int*)  d_in[8];
    const int*   d_eid   = (const int*)  d_in[9];
    const float* d_t     = (const float*)d_in[10];
    const float* tw      = (const float*)d_in[11];
    const float* tb      = (const float*)d_in[12];
    const float* W       = (const float*)d_in[13];
    const float* bout    = (const float*)d_in[14];
    float* out = (float*)d_out;

    spe_fused<<<2048, BLOCK, 0, stream>>>(
        nodef, edgef, src_ids, dst_ids, itimes,
        s_nbr, s_eid, s_t, d_nbr, d_eid, d_t,
        tw, tb, W, bout, out);
}